// Round 5
// baseline (983.328 us; speedup 1.0000x reference)
//
#include <hip/hip_runtime.h>
#include <hip/hip_bf16.h>

#define E_ 8
#define H_ 2048
#define I_ 1024
#define T_ 16384
#define BK 64
#define BM 256
#define MT_ (T_ / BM + E_)   // 72 max m-tiles (64 full + up to 8 partial)
#define SLOT 16384           // ushorts per LDS slot (32 KB); 4 slots = 128 KB

typedef __bf16 bf16x8 __attribute__((ext_vector_type(8)));
typedef float f32x4 __attribute__((ext_vector_type(4)));

__device__ __forceinline__ unsigned short f2bf(float f) {
  unsigned int x = __float_as_uint(f);
  x += 0x7FFFu + ((x >> 16) & 1u);   // round-to-nearest-even
  return (unsigned short)(x >> 16);
}

__device__ __forceinline__ void gl_lds16(const void* g, void* s) {
  __builtin_amdgcn_global_load_lds(
      (const __attribute__((address_space(1))) void*)g,
      (__attribute__((address_space(3))) void*)s, 16, 0, 0);
}

// Raw barrier (no vmcnt(0) drain) + sched fence: nothing crosses the
// publication point. The weight-DMA retire is implicit: A-fragment loads of
// tile t are issued AFTER the GU(t) DMAs, so the compiler's position-counted
// vmcnt before each MFMA cluster retires all older DMAs while leaving the
// t+2 prefetch in flight (T4 counted-vmcnt, compiler-generated).
#define BAR                            \
  do {                                 \
    __builtin_amdgcn_s_barrier();      \
    __builtin_amdgcn_sched_barrier(0); \
  } while (0)

// MFMA cluster wrapped in setprio (T5). NI = B-fragment count.
#define MFMA_CL(ACC, AF, BF, NI)                                                \
  do {                                                                          \
    __builtin_amdgcn_s_setprio(1);                                              \
    _Pragma("unroll") for (int ks = 0; ks < 2; ks++)                            \
    _Pragma("unroll") for (int mi = 0; mi < 4; mi++)                            \
    _Pragma("unroll") for (int ni = 0; ni < NI; ni++)                           \
      ACC[mi][ni] = __builtin_amdgcn_mfma_f32_16x16x32_bf16(                    \
          AF[mi][ks], BF[ni][ks], ACC[mi][ni], 0, 0, 0);                        \
    __builtin_amdgcn_s_setprio(0);                                              \
  } while (0)

__device__ __forceinline__ bool find_tile(const int* gs, int tile, int& e,
                                          int& row0, int& rowEnd) {
  int base = 0, tb = 0;
  e = -1;
  for (int i = 0; i < E_; i++) {
    int g = gs[i];
    int nt = (g + BM - 1) >> 8;
    if (e < 0 && tile < tb + nt) {
      e = i;
      row0 = base + (tile - tb) * BM;
      rowEnd = base + g;
    }
    tb += nt;
    base += g;
  }
  return e >= 0;
}

// ---------------- conversion kernels (unchanged) ----------------

__global__ void cvt_hs(const float* __restrict__ in, ushort* __restrict__ out) {
  size_t i = ((size_t)blockIdx.x * 256 + threadIdx.x) * 8;
  float4 a = *(const float4*)(in + i);
  float4 b = *(const float4*)(in + i + 4);
  union { ushort u[8]; uint4 v; } p;
  p.u[0] = f2bf(a.x); p.u[1] = f2bf(a.y); p.u[2] = f2bf(a.z); p.u[3] = f2bf(a.w);
  p.u[4] = f2bf(b.x); p.u[5] = f2bf(b.y); p.u[6] = f2bf(b.z); p.u[7] = f2bf(b.w);
  *(uint4*)(out + i) = p.v;
}

__global__ void cvt_tr(const float* __restrict__ in, ushort* __restrict__ out,
                       int K, int N) {
  __shared__ ushort tile[64][65];
  int n0 = blockIdx.x * 64, k0 = blockIdx.y * 64;
  const float* src = in + (size_t)blockIdx.z * K * N;
  ushort* dst = out + (size_t)blockIdx.z * K * N;
  int t = threadIdx.x;
  int rb = t >> 4, c4 = (t & 15) * 4;
#pragma unroll
  for (int i = 0; i < 4; i++) {
    int r = rb + i * 16;
    float4 v = *(const float4*)(src + (size_t)(k0 + r) * N + n0 + c4);
    tile[r][c4 + 0] = f2bf(v.x);
    tile[r][c4 + 1] = f2bf(v.y);
    tile[r][c4 + 2] = f2bf(v.z);
    tile[r][c4 + 3] = f2bf(v.w);
  }
  __syncthreads();
#pragma unroll
  for (int i = 0; i < 2; i++) {
    int c = t + i * 256;
    int n = c >> 3, kc = c & 7;
    union { ushort u[8]; uint4 v; } p;
#pragma unroll
    for (int j = 0; j < 8; j++) p.u[j] = tile[kc * 8 + j][n];
    *(uint4*)(dst + (size_t)(n0 + n) * K + k0 + kc * 8) = p.v;
  }
}

// ---------------- fused gate/up GEMM + SwiGLU: 256x128 tile, 8 waves ----------------
// A-fragments come DIRECTLY from global (L1/L2-served; removes 32 KB of LDS
// writes + 128 KB of LDS reads per block-K-tile -- the 4x wn read
// amplification). LDS holds only G,U (32 KB/slot), 4 slots, staged 2 K-tiles
// ahead. One raw barrier per K-tile; all waits are compiler-generated counted
// vmcnt (A loads) / lgkmcnt (B frags).
__global__ __launch_bounds__(512, 2) void gemm_gateup(
    const ushort* __restrict__ A, const ushort* __restrict__ BgT,
    const ushort* __restrict__ BuT, const int* __restrict__ gs,
    ushort* __restrict__ Hb) {
  extern __shared__ __align__(16) ushort ls[];

  int e, row0, rowEnd;
  if (!find_tile(gs, blockIdx.x, e, row0, rowEnd)) return;
  const int n0 = blockIdx.y * 128;

  const int t = threadIdx.x;
  const int lane = t & 63;
  const int w = t >> 6;
  const int wm = w & 1, wn = w >> 1;  // 2M x 4N wave grid
  const int ldW = w * 512;

  // G/U staging source offsets (pre-swizzled): chunk c -> r=c>>3, kc=(c&7)^(r&7)
  int oB[2];
#pragma unroll
  for (int l = 0; l < 2; l++) {
    int c = l * 512 + t;
    int r = c >> 3, kc = (c & 7) ^ (r & 7);
    oB[l] = (e * I_ + n0 + r) * H_ + kc * 8;
  }

  const int l15 = lane & 15, l7 = lane & 7, lk = lane >> 4;
  const int s0 = (lk ^ l7) * 8, s1 = ((lk + 4) ^ l7) * 8;
  const int brow = (wn * 32 + l15) * 64;

  // affine A addressing: clamp the tile base (not per-row) so fragment rows
  // stay in-bounds; epilogue guards row >= row0 for the clamped case.
  const int rowB = (row0 > T_ - BM) ? (T_ - BM) : row0;
  const int aBase = (rowB + wm * 64 + l15) * H_ + lk * 8;

  f32x4 accG0[4][2], accG1[4][2], accU0[4][2], accU1[4][2];
#pragma unroll
  for (int mi = 0; mi < 4; mi++)
#pragma unroll
    for (int ni = 0; ni < 2; ni++) {
      accG0[mi][ni] = (f32x4){0.f, 0.f, 0.f, 0.f};
      accG1[mi][ni] = (f32x4){0.f, 0.f, 0.f, 0.f};
      accU0[mi][ni] = (f32x4){0.f, 0.f, 0.f, 0.f};
      accU1[mi][ni] = (f32x4){0.f, 0.f, 0.f, 0.f};
    }

  // prologue: stage G,U for tiles 0 and 1 (slots 0,1), retire tile 0
#pragma unroll
  for (int tp = 0; tp < 2; tp++) {
    ushort* sq = ls + tp * SLOT;
    gl_lds16(BgT + oB[0] + tp * BK, sq + 0 + ldW);
    gl_lds16(BgT + oB[1] + tp * BK, sq + 4096 + ldW);
    gl_lds16(BuT + oB[0] + tp * BK, sq + 8192 + ldW);
    gl_lds16(BuT + oB[1] + tp * BK, sq + 8192 + 4096 + ldW);
  }
  asm volatile("s_waitcnt vmcnt(4)" ::: "memory");

#pragma unroll 4
  for (int tt = 0; tt < H_ / BK; tt++) {
    const ushort* sa = ls + (tt & 3) * SLOT;
    ushort* sq = ls + ((tt + 2) & 3) * SLOT;
    int t2 = tt + 2; if (t2 > H_ / BK - 1) t2 = H_ / BK - 1;
    const int kn = t2 * BK;

    BAR;   // slot tt published (all waves retired GU(tt) during tt-1)

    bf16x8 afL[4][2], afH[4][2], gf[2][2], uf[2][2];
    const ushort* pa = A + aBase + tt * BK;
#pragma unroll
    for (int mi = 0; mi < 4; mi++) {
      afL[mi][0] = *(const bf16x8*)(pa + mi * 16 * H_);
      afL[mi][1] = *(const bf16x8*)(pa + mi * 16 * H_ + 32);
    }
#pragma unroll
    for (int mi = 0; mi < 4; mi++) {
      afH[mi][0] = *(const bf16x8*)(pa + (128 + mi * 16) * H_);
      afH[mi][1] = *(const bf16x8*)(pa + (128 + mi * 16) * H_ + 32);
    }
    // stage G,U for tile tt+2 (2-tile cover, never drained in-loop)
    gl_lds16(BgT + oB[0] + kn, sq + 0 + ldW);
    gl_lds16(BgT + oB[1] + kn, sq + 4096 + ldW);
    gl_lds16(BuT + oB[0] + kn, sq + 8192 + ldW);
    gl_lds16(BuT + oB[1] + kn, sq + 8192 + 4096 + ldW);
    // B fragments from LDS (swizzled, conflict-free)
#pragma unroll
    for (int ni = 0; ni < 2; ni++) {
      gf[ni][0] = *(const bf16x8*)(sa + brow + ni * 1024 + s0);
      gf[ni][1] = *(const bf16x8*)(sa + brow + ni * 1024 + s1);
      uf[ni][0] = *(const bf16x8*)(sa + 8192 + brow + ni * 1024 + s0);
      uf[ni][1] = *(const bf16x8*)(sa + 8192 + brow + ni * 1024 + s1);
    }
    MFMA_CL(accG0, afL, gf, 2);
    MFMA_CL(accU0, afL, uf, 2);
    MFMA_CL(accG1, afH, gf, 2);
    MFMA_CL(accU1, afH, uf, 2);
  }

  // epilogue: h = silu(g)*u, bf16 store. C/D: col=lane&15, row=(lane>>4)*4+r
  const int cr = rowB + wm * 64 + (lk << 2);
  const int cc = n0 + wn * 32 + l15;
#pragma unroll
  for (int mh = 0; mh < 2; mh++)
#pragma unroll
    for (int mi = 0; mi < 4; mi++)
#pragma unroll
      for (int ni = 0; ni < 2; ni++)
#pragma unroll
        for (int r = 0; r < 4; r++) {
          int row = cr + mh * 128 + mi * 16 + r;
          if (row >= row0 && row < rowEnd) {
            float g = mh ? accG1[mi][ni][r] : accG0[mi][ni][r];
            float u = mh ? accU1[mi][ni][r] : accU0[mi][ni][r];
            float h = (g / (1.0f + __expf(-g))) * u;
            Hb[(size_t)row * I_ + cc + ni * 16] = f2bf(h);
          }
        }
}

// ---------------- down GEMM: 256x256 tile, 8 waves ----------------
// Same A-direct structure. LDS holds only B (32 KB/slot), 4 slots. Per-wave
// output 128x64 (acc 128), B frags bf[4][2].
__global__ __launch_bounds__(512, 2) void gemm_down(
    const ushort* __restrict__ A, const ushort* __restrict__ BdT,
    const int* __restrict__ gs, float* __restrict__ Out) {
  extern __shared__ __align__(16) ushort ls[];

  int e, row0, rowEnd;
  if (!find_tile(gs, blockIdx.x, e, row0, rowEnd)) return;
  const int n0 = blockIdx.y * 256;

  const int t = threadIdx.x;
  const int lane = t & 63;
  const int w = t >> 6;
  const int wm = w & 1, wn = w >> 1;
  const int ldW = w * 512;

  int oB[4];
#pragma unroll
  for (int l = 0; l < 4; l++) {
    int c = l * 512 + t;
    int r = c >> 3, kc = (c & 7) ^ (r & 7);
    oB[l] = (e * H_ + n0 + r) * I_ + kc * 8;
  }

  const int l15 = lane & 15, l7 = lane & 7, lk = lane >> 4;
  const int s0 = (lk ^ l7) * 8, s1 = ((lk + 4) ^ l7) * 8;
  const int brow = (wn * 64 + l15) * 64;

  const int rowB = (row0 > T_ - BM) ? (T_ - BM) : row0;
  const int aBase = (rowB + wm * 64 + l15) * I_ + lk * 8;

  f32x4 accL[4][4], accH[4][4];
#pragma unroll
  for (int mi = 0; mi < 4; mi++)
#pragma unroll
    for (int ni = 0; ni < 4; ni++) {
      accL[mi][ni] = (f32x4){0.f, 0.f, 0.f, 0.f};
      accH[mi][ni] = (f32x4){0.f, 0.f, 0.f, 0.f};
    }

  // prologue: stage B for tiles 0 and 1, retire tile 0
#pragma unroll
  for (int tp = 0; tp < 2; tp++) {
    ushort* sq = ls + tp * SLOT;
#pragma unroll
    for (int l = 0; l < 4; l++)
      gl_lds16(BdT + oB[l] + tp * BK, sq + l * 4096 + ldW);
  }
  asm volatile("s_waitcnt vmcnt(4)" ::: "memory");

#pragma unroll 4
  for (int tt = 0; tt < I_ / BK; tt++) {
    const ushort* sa = ls + (tt & 3) * SLOT;
    ushort* sq = ls + ((tt + 2) & 3) * SLOT;
    int t2 = tt + 2; if (t2 > I_ / BK - 1) t2 = I_ / BK - 1;
    const int kn = t2 * BK;

    BAR;

    bf16x8 afL[4][2], afH[4][2], bf[4][2];
    const ushort* pa = A + aBase + tt * BK;
#pragma unroll
    for (int mi = 0; mi < 4; mi++) {
      afL[mi][0] = *(const bf16x8*)(pa + mi * 16 * I_);
      afL[mi][1] = *(const bf16x8*)(pa + mi * 16 * I_ + 32);
    }
#pragma unroll
    for (int mi = 0; mi < 4; mi++) {
      afH[mi][0] = *(const bf16x8*)(pa + (128 + mi * 16) * I_);
      afH[mi][1] = *(const bf16x8*)(pa + (128 + mi * 16) * I_ + 32);
    }
#pragma unroll
    for (int l = 0; l < 4; l++)
      gl_lds16(BdT + oB[l] + kn, sq + l * 4096 + ldW);
#pragma unroll
    for (int ni = 0; ni < 4; ni++) {
      bf[ni][0] = *(const bf16x8*)(sa + brow + ni * 1024 + s0);
      bf[ni][1] = *(const bf16x8*)(sa + brow + ni * 1024 + s1);
    }
    MFMA_CL(accL, afL, bf, 4);
    MFMA_CL(accH, afH, bf, 4);
  }

  const int cr = rowB + wm * 64 + (lk << 2);
  const int cc = n0 + wn * 64 + l15;
#pragma unroll
  for (int mh = 0; mh < 2; mh++)
#pragma unroll
    for (int mi = 0; mi < 4; mi++)
#pragma unroll
      for (int ni = 0; ni < 4; ni++)
#pragma unroll
        for (int r = 0; r < 4; r++) {
          int row = cr + mh * 128 + mi * 16 + r;
          if (row >= row0 && row < rowEnd) {
            float v = mh ? accH[mi][ni][r] : accL[mi][ni][r];
            Out[(size_t)row * H_ + cc + ni * 16] = v;
          }
        }
}

extern "C" void kernel_launch(void* const* d_in, const int* in_sizes, int n_in,
                              void* d_out, int out_size, void* d_ws, size_t ws_size,
                              hipStream_t stream) {
  const float* hs = (const float*)d_in[0];
  const float* gw = (const float*)d_in[1];
  const float* uw = (const float*)d_in[2];
  const float* dw = (const float*)d_in[3];
  const int* gs = (const int*)d_in[4];
  float* out = (float*)d_out;

  ushort* hsb = (ushort*)d_ws;                       // [T,H]
  ushort* wgT = hsb + (size_t)T_ * H_;               // [E,I,H]
  ushort* wuT = wgT + (size_t)E_ * H_ * I_;          // [E,I,H]
  ushort* wdT = wuT + (size_t)E_ * H_ * I_;          // [E,H,I]
  ushort* hb  = wdT + (size_t)E_ * H_ * I_;          // [T,I]

  (void)hipFuncSetAttribute(reinterpret_cast<const void*>(gemm_gateup),
                            hipFuncAttributeMaxDynamicSharedMemorySize, 131072);
  (void)hipFuncSetAttribute(reinterpret_cast<const void*>(gemm_down),
                            hipFuncAttributeMaxDynamicSharedMemorySize, 131072);

  cvt_hs<<<((size_t)T_ * H_) / (256 * 8), 256, 0, stream>>>(hs, hsb);
  cvt_tr<<<dim3(I_ / 64, H_ / 64, E_), 256, 0, stream>>>(gw, wgT, H_, I_);
  cvt_tr<<<dim3(I_ / 64, H_ / 64, E_), 256, 0, stream>>>(uw, wuT, H_, I_);
  cvt_tr<<<dim3(H_ / 64, I_ / 64, E_), 256, 0, stream>>>(dw, wdT, I_, H_);

  gemm_gateup<<<dim3(MT_, I_ / 128), 512, 131072, stream>>>(hsb, wgT, wuT, gs, hb);
  gemm_down<<<dim3(MT_, H_ / 256), 512, 131072, stream>>>(hb, wdT, gs, out);
}

// Round 6
// 617.522 us; speedup vs baseline: 1.5924x; 1.5924x over previous
//
#include <hip/hip_runtime.h>
#include <hip/hip_bf16.h>

#define E_ 8
#define H_ 2048
#define I_ 1024
#define T_ 16384
#define BM 256
#define MT_ (T_ / BM + E_)   // 72 m-tiles (64 full + up to 8 idle/partial)
#define SLOTU 12288          // ushorts per LDS slot (24 KB); 3 slots = 72 KB

typedef __bf16 bf16x8 __attribute__((ext_vector_type(8)));
typedef float f32x4 __attribute__((ext_vector_type(4)));

__device__ __forceinline__ unsigned short f2bf(float f) {
  unsigned int x = __float_as_uint(f);
  x += 0x7FFFu + ((x >> 16) & 1u);   // round-to-nearest-even
  return (unsigned short)(x >> 16);
}

__device__ __forceinline__ void gl_lds16(const void* g, void* s) {
  __builtin_amdgcn_global_load_lds(
      (const __attribute__((address_space(1))) void*)g,
      (__attribute__((address_space(3))) void*)s, 16, 0, 0);
}

// Uniform counted wait: 3 DMAs/wave/K-step; at iter top outstanding = 6
// (t and t+1); vmcnt(3) retires exactly tile t's. Never drains to 0 (T4).
#define VMCNT3 asm volatile("s_waitcnt vmcnt(3)" ::: "memory")
// Raw barrier (no vmcnt(0) drain) + sched fence (nothing hoists above it).
#define BAR                            \
  do {                                 \
    __builtin_amdgcn_s_barrier();      \
    __builtin_amdgcn_sched_barrier(0); \
  } while (0)

__device__ __forceinline__ bool find_tile(const int* gs, int tile, int& e,
                                          int& row0, int& rowEnd) {
  int base = 0, tb = 0;
  e = -1;
  for (int i = 0; i < E_; i++) {
    int g = gs[i];
    int nt = (g + BM - 1) >> 8;
    if (e < 0 && tile < tb + nt) {
      e = i;
      row0 = base + (tile - tb) * BM;
      rowEnd = base + g;
    }
    tb += nt;
    base += g;
  }
  return e >= 0;
}

// ---------------- conversion kernels (unchanged) ----------------

__global__ void cvt_hs(const float* __restrict__ in, ushort* __restrict__ out) {
  size_t i = ((size_t)blockIdx.x * 256 + threadIdx.x) * 8;
  float4 a = *(const float4*)(in + i);
  float4 b = *(const float4*)(in + i + 4);
  union { ushort u[8]; uint4 v; } p;
  p.u[0] = f2bf(a.x); p.u[1] = f2bf(a.y); p.u[2] = f2bf(a.z); p.u[3] = f2bf(a.w);
  p.u[4] = f2bf(b.x); p.u[5] = f2bf(b.y); p.u[6] = f2bf(b.z); p.u[7] = f2bf(b.w);
  *(uint4*)(out + i) = p.v;
}

__global__ void cvt_tr(const float* __restrict__ in, ushort* __restrict__ out,
                       int K, int N) {
  __shared__ ushort tile[64][65];
  int n0 = blockIdx.x * 64, k0 = blockIdx.y * 64;
  const float* src = in + (size_t)blockIdx.z * K * N;
  ushort* dst = out + (size_t)blockIdx.z * K * N;
  int t = threadIdx.x;
  int rb = t >> 4, c4 = (t & 15) * 4;
#pragma unroll
  for (int i = 0; i < 4; i++) {
    int r = rb + i * 16;
    float4 v = *(const float4*)(src + (size_t)(k0 + r) * N + n0 + c4);
    tile[r][c4 + 0] = f2bf(v.x);
    tile[r][c4 + 1] = f2bf(v.y);
    tile[r][c4 + 2] = f2bf(v.z);
    tile[r][c4 + 3] = f2bf(v.w);
  }
  __syncthreads();
#pragma unroll
  for (int i = 0; i < 2; i++) {
    int c = t + i * 256;
    int n = c >> 3, kc = c & 7;
    union { ushort u[8]; uint4 v; } p;
#pragma unroll
    for (int j = 0; j < 8; j++) p.u[j] = tile[kc * 8 + j][n];
    *(uint4*)(dst + (size_t)(n0 + n) * K + k0 + kc * 8) = p.v;
  }
}

// ------------- fused gate/up GEMM + SwiGLU: 256x64 tile, 8 waves, BK=32 -------------
// 16-waves/CU design: acc 64 + frag 16 + ~50 overhead <= 128 unified regs ->
// 2 independent blocks/CU (launch_bounds(512,4)); inter-block TLP absorbs
// sync stalls (m114). LDS = 3 rotating 24KB slots (A 16K, G 4K, U 4K), staged
// 2 K-steps ahead: slot(t+2) != slot(t) mod 3, so no WAR barrier needed ->
// ONE barrier + ONE vmcnt(3) per K-step. Swizzle: 64B rows, 4 slots of 16B,
// phys = slot ^ (row&3); b128 reads land 8 lanes/bank (wave64 optimum).
__global__ __launch_bounds__(512, 4) void gemm_gateup(
    const ushort* __restrict__ A, const ushort* __restrict__ BgT,
    const ushort* __restrict__ BuT, const int* __restrict__ gs,
    ushort* __restrict__ Hb) {
  extern __shared__ __align__(16) ushort ls[];

  int e, row0, rowEnd;
  if (!find_tile(gs, blockIdx.x, e, row0, rowEnd)) return;
  const int n0 = blockIdx.y * 64;

  const int t = threadIdx.x;
  const int lane = t & 63;
  const int w = t >> 6;
  const int wm = w & 3, wn = w >> 2;  // 4M x 2N wave grid

  // staging: one shared swizzled voffset serves A-lo/A-hi/G/U
  const int cr = t >> 2;                        // chunk row 0..127
  const int sw8 = ((t & 3) ^ (cr & 3)) * 8;     // swizzled 8-elem k-slot
  const int voff = cr * H_ + sw8;
  const int dA0 = t * 8, dA1 = 4096 + t * 8, dGU = 8192 + t * 8;

  const int rowB = (row0 > T_ - BM) ? (T_ - BM) : row0;
  const ushort* bA0 = A + (size_t)rowB * H_;
  const ushort* bA1 = bA0 + (size_t)128 * H_;
  // waves 0-3 stage G rows (cr<64), waves 4-7 stage U rows (cr-64)
  const ushort* bGU = (w < 4) ? BgT + (size_t)(e * I_ + n0) * H_
                              : BuT + (size_t)(e * I_ + n0) * H_ - (size_t)64 * H_;

  // fragment addressing: single per-lane base + compile-time imm offsets
  const int l15 = lane & 15, lk = lane >> 4;
  const int pl = l15 * 32 + (lk ^ (l15 & 3)) * 8;
  const int aoff = wm * 2048 + pl;              // + mi*512
  const int boff = 8192 + wn * 1024 + pl;       // G: +ni*512 ; U: +2048+ni*512

  f32x4 accG[4][2], accU[4][2];
#pragma unroll
  for (int mi = 0; mi < 4; mi++)
#pragma unroll
    for (int ni = 0; ni < 2; ni++) {
      accG[mi][ni] = (f32x4){0.f, 0.f, 0.f, 0.f};
      accU[mi][ni] = (f32x4){0.f, 0.f, 0.f, 0.f};
    }

  // prologue: stage K-steps 0,1 into slots 0,1 (6 DMAs outstanding)
#pragma unroll
  for (int tp = 0; tp < 2; tp++) {
    ushort* sq = ls + tp * SLOTU;
    gl_lds16(bA0 + voff + tp * 32, sq + dA0);
    gl_lds16(bA1 + voff + tp * 32, sq + dA1);
    gl_lds16(bGU + voff + tp * 32, sq + dGU);
  }

#pragma unroll 3
  for (int tt = 0; tt < H_ / 32; tt++) {
    const ushort* sa = ls + (tt % 3) * SLOTU;
    ushort* sq = ls + ((tt + 2) % 3) * SLOTU;
    int t2 = tt + 2; if (t2 > H_ / 32 - 1) t2 = H_ / 32 - 1;
    const int kn = t2 * 32;

    VMCNT3;   // slot tt's 3 DMAs retired (per-wave)
    BAR;      // collective: slot tt published; slot (tt+2)%3 free (reads done pre-MFMA of tt-1)

    gl_lds16(bA0 + voff + kn, sq + dA0);
    gl_lds16(bA1 + voff + kn, sq + dA1);
    gl_lds16(bGU + voff + kn, sq + dGU);

    bf16x8 af[4], gf[2], uf[2];
#pragma unroll
    for (int mi = 0; mi < 4; mi++)
      af[mi] = *(const bf16x8*)(sa + aoff + mi * 512);
#pragma unroll
    for (int ni = 0; ni < 2; ni++) {
      gf[ni] = *(const bf16x8*)(sa + boff + ni * 512);
      uf[ni] = *(const bf16x8*)(sa + boff + 2048 + ni * 512);
    }

    __builtin_amdgcn_s_setprio(1);
#pragma unroll
    for (int mi = 0; mi < 4; mi++)
#pragma unroll
      for (int ni = 0; ni < 2; ni++) {
        accG[mi][ni] = __builtin_amdgcn_mfma_f32_16x16x32_bf16(af[mi], gf[ni], accG[mi][ni], 0, 0, 0);
        accU[mi][ni] = __builtin_amdgcn_mfma_f32_16x16x32_bf16(af[mi], uf[ni], accU[mi][ni], 0, 0, 0);
      }
    __builtin_amdgcn_s_setprio(0);
  }

  // epilogue: h = silu(g)*u. C/D: col=lane&15, row=(lane>>4)*4+reg
  const int orow = rowB + wm * 64 + lk * 4;
  const int ocol = n0 + wn * 32 + l15;
#pragma unroll
  for (int mi = 0; mi < 4; mi++)
#pragma unroll
    for (int ni = 0; ni < 2; ni++)
#pragma unroll
      for (int r = 0; r < 4; r++) {
        int row = orow + mi * 16 + r;
        if (row >= row0 && row < rowEnd) {
          float g = accG[mi][ni][r];
          float u = accU[mi][ni][r];
          float h = (g / (1.0f + __expf(-g))) * u;
          Hb[(size_t)row * I_ + ocol + ni * 16] = f2bf(h);
        }
      }
}

// ---------------- down GEMM: 256x128 tile, 8 waves, BK=32 ----------------
// Same 16-waves/CU structure. LDS slot 24 KB: A [0,8192) + B [8192,12288).
// acc[4][4]=64, frags af[4]+bf[4]=16.
__global__ __launch_bounds__(512, 4) void gemm_down(
    const ushort* __restrict__ A, const ushort* __restrict__ BdT,
    const int* __restrict__ gs, float* __restrict__ Out) {
  extern __shared__ __align__(16) ushort ls[];

  int e, row0, rowEnd;
  if (!find_tile(gs, blockIdx.x, e, row0, rowEnd)) return;
  const int n0 = blockIdx.y * 128;

  const int t = threadIdx.x;
  const int lane = t & 63;
  const int w = t >> 6;
  const int wm = w & 3, wn = w >> 2;  // 4M x 2N

  const int cr = t >> 2;
  const int sw8 = ((t & 3) ^ (cr & 3)) * 8;
  const int voff = cr * I_ + sw8;
  const int dA0 = t * 8, dA1 = 4096 + t * 8, dB = 8192 + t * 8;

  const int rowB = (row0 > T_ - BM) ? (T_ - BM) : row0;
  const ushort* bA0 = A + (size_t)rowB * I_;
  const ushort* bA1 = bA0 + (size_t)128 * I_;
  const ushort* bB = BdT + (size_t)(e * H_ + n0) * I_;

  const int l15 = lane & 15, lk = lane >> 4;
  const int pl = l15 * 32 + (lk ^ (l15 & 3)) * 8;
  const int aoff = wm * 2048 + pl;          // + mi*512
  const int boff = 8192 + wn * 2048 + pl;   // + ni*512

  f32x4 acc[4][4];
#pragma unroll
  for (int mi = 0; mi < 4; mi++)
#pragma unroll
    for (int ni = 0; ni < 4; ni++) acc[mi][ni] = (f32x4){0.f, 0.f, 0.f, 0.f};

#pragma unroll
  for (int tp = 0; tp < 2; tp++) {
    ushort* sq = ls + tp * SLOTU;
    gl_lds16(bA0 + voff + tp * 32, sq + dA0);
    gl_lds16(bA1 + voff + tp * 32, sq + dA1);
    gl_lds16(bB + voff + tp * 32, sq + dB);
  }

#pragma unroll 3
  for (int tt = 0; tt < I_ / 32; tt++) {
    const ushort* sa = ls + (tt % 3) * SLOTU;
    ushort* sq = ls + ((tt + 2) % 3) * SLOTU;
    int t2 = tt + 2; if (t2 > I_ / 32 - 1) t2 = I_ / 32 - 1;
    const int kn = t2 * 32;

    VMCNT3; BAR;

    gl_lds16(bA0 + voff + kn, sq + dA0);
    gl_lds16(bA1 + voff + kn, sq + dA1);
    gl_lds16(bB + voff + kn, sq + dB);

    bf16x8 af[4], bf[4];
#pragma unroll
    for (int mi = 0; mi < 4; mi++)
      af[mi] = *(const bf16x8*)(sa + aoff + mi * 512);
#pragma unroll
    for (int ni = 0; ni < 4; ni++)
      bf[ni] = *(const bf16x8*)(sa + boff + ni * 512);

    __builtin_amdgcn_s_setprio(1);
#pragma unroll
    for (int mi = 0; mi < 4; mi++)
#pragma unroll
      for (int ni = 0; ni < 4; ni++)
        acc[mi][ni] = __builtin_amdgcn_mfma_f32_16x16x32_bf16(af[mi], bf[ni], acc[mi][ni], 0, 0, 0);
    __builtin_amdgcn_s_setprio(0);
  }

  const int orow = rowB + wm * 64 + lk * 4;
  const int ocol = n0 + wn * 64 + l15;
#pragma unroll
  for (int mi = 0; mi < 4; mi++)
#pragma unroll
    for (int ni = 0; ni < 4; ni++)
#pragma unroll
      for (int r = 0; r < 4; r++) {
        int row = orow + mi * 16 + r;
        if (row >= row0 && row < rowEnd)
          Out[(size_t)row * H_ + ocol + ni * 16] = acc[mi][ni][r];
      }
}

extern "C" void kernel_launch(void* const* d_in, const int* in_sizes, int n_in,
                              void* d_out, int out_size, void* d_ws, size_t ws_size,
                              hipStream_t stream) {
  const float* hs = (const float*)d_in[0];
  const float* gw = (const float*)d_in[1];
  const float* uw = (const float*)d_in[2];
  const float* dw = (const float*)d_in[3];
  const int* gs = (const int*)d_in[4];
  float* out = (float*)d_out;

  ushort* hsb = (ushort*)d_ws;                       // [T,H]
  ushort* wgT = hsb + (size_t)T_ * H_;               // [E,I,H]
  ushort* wuT = wgT + (size_t)E_ * H_ * I_;          // [E,I,H]
  ushort* wdT = wuT + (size_t)E_ * H_ * I_;          // [E,H,I]
  ushort* hb  = wdT + (size_t)E_ * H_ * I_;          // [T,I]

  (void)hipFuncSetAttribute(reinterpret_cast<const void*>(gemm_gateup),
                            hipFuncAttributeMaxDynamicSharedMemorySize, 73728);
  (void)hipFuncSetAttribute(reinterpret_cast<const void*>(gemm_down),
                            hipFuncAttributeMaxDynamicSharedMemorySize, 73728);

  cvt_hs<<<((size_t)T_ * H_) / (256 * 8), 256, 0, stream>>>(hs, hsb);
  cvt_tr<<<dim3(I_ / 64, H_ / 64, E_), 256, 0, stream>>>(gw, wgT, H_, I_);
  cvt_tr<<<dim3(I_ / 64, H_ / 64, E_), 256, 0, stream>>>(uw, wuT, H_, I_);
  cvt_tr<<<dim3(H_ / 64, I_ / 64, E_), 256, 0, stream>>>(dw, wdT, I_, H_);

  // grid (m, n): linear id % 8 = m % 8 (gridDim.x = 72 ≡ 0 mod 8) -> all
  // n-blocks of one m-tile share an XCD L2 for the A panel.
  gemm_gateup<<<dim3(MT_, I_ / 64), 512, 73728, stream>>>(hsb, wgT, wuT, gs, hb);
  gemm_down<<<dim3(MT_, H_ / 128), 512, 73728, stream>>>(hb, wdT, gs, out);
}